// Round 10
// baseline (405.157 us; speedup 1.0000x reference)
//
#include <hip/hip_runtime.h>
#include <hip/hip_bf16.h>

// HiPPO-LegT parallel chunked scan, round 10.
// = R9 chain verbatim; out_gemm block->tile mapping changed to
//   "XCD owns an mt-slice, sweeps nt": per-XCD Ht slice is L2-resident,
//   Gt panels stream in lockstep across XCDs (L3-shared 8-way).
//
// ws layout (floats):
//   P   : A^1..A^64          (64 * 65536)
//   Kv  : A^j B, j=0..63     (64 * 256)
//   e   : scan buffer 0      (64 * 256 * 64)
//   w2  : scan buffer 1      (64 * 256 * 64)
//   MS  : squaring ping-pong (2 * 65536)
//   Ht  : bf16 [4096][640]   (hi 0..319 | lo 320..639)   (ushort)
//   Gt  : bf16 [16384][640]                               (ushort)

#define MATF 65536

typedef __attribute__((ext_vector_type(8))) short short8;
typedef __attribute__((ext_vector_type(4))) float f32x4;

__device__ __forceinline__ unsigned short f2bf(float x) {
  union { __hip_bfloat16 h; unsigned short u; } cv;
  cv.h = __float2bfloat16(x);
  return cv.u;
}
__device__ __forceinline__ float bf2f(unsigned short u) {
  union { unsigned short u; __hip_bfloat16 h; } cv;
  cv.u = u;
  return __bfloat162float(cv.h);
}

__device__ __forceinline__ void load16_lds(const void* gsrc, void* ldst) {
  __builtin_amdgcn_global_load_lds(
      (const __attribute__((address_space(1))) unsigned int*)gsrc,
      (__attribute__((address_space(3))) unsigned int*)ldst,
      16, 0, 0);
}

// ---------- batched 256x256x256 GEMM: Z[g] = X @ Y[g] (fp32) ----------
__global__ __launch_bounds__(256) void gemm_nn_batch(
    const float* __restrict__ X, const float* __restrict__ Ys,
    float* __restrict__ Zs, int count)
{
  int g    = blockIdx.x >> 4;
  int tile = blockIdx.x & 15;
  if (g >= count) return;
  const float* Y = Ys + (size_t)g * MATF;
  float*       Z = Zs + (size_t)g * MATF;
  int tr = (tile >> 2) * 64;
  int tc = (tile & 3) * 64;

  __shared__ float As[64][33];
  __shared__ float Bs[32][65];
  int tid = threadIdx.x;
  int tx = tid & 15, ty = tid >> 4;
  float acc[4][4] = {};

  for (int k0 = 0; k0 < 256; k0 += 32) {
#pragma unroll
    for (int p = 0; p < 2; ++p) {
      int idx = tid + p * 256;
      int r = idx >> 3, c4 = (idx & 7) * 4;
      float4 v = *(const float4*)(X + (size_t)(tr + r) * 256 + k0 + c4);
      As[r][c4 + 0] = v.x; As[r][c4 + 1] = v.y; As[r][c4 + 2] = v.z; As[r][c4 + 3] = v.w;
    }
#pragma unroll
    for (int p = 0; p < 2; ++p) {
      int idx = tid + p * 256;
      int r = idx >> 4, c4 = (idx & 15) * 4;
      float4 v = *(const float4*)(Y + (size_t)(k0 + r) * 256 + tc + c4);
      Bs[r][c4 + 0] = v.x; Bs[r][c4 + 1] = v.y; Bs[r][c4 + 2] = v.z; Bs[r][c4 + 3] = v.w;
    }
    __syncthreads();
#pragma unroll
    for (int kk = 0; kk < 32; ++kk) {
      float a[4], b[4];
#pragma unroll
      for (int u = 0; u < 4; ++u) a[u] = As[ty * 4 + u][kk];
#pragma unroll
      for (int v = 0; v < 4; ++v) b[v] = Bs[kk][tx * 4 + v];
#pragma unroll
      for (int u = 0; u < 4; ++u)
#pragma unroll
        for (int v = 0; v < 4; ++v) acc[u][v] += a[u] * b[v];
    }
    __syncthreads();
  }
#pragma unroll
  for (int u = 0; u < 4; ++u)
#pragma unroll
    for (int v = 0; v < 4; ++v)
      Z[(size_t)(tr + ty * 4 + u) * 256 + tc + tx * 4 + v] = acc[u][v];
}

// ---------- first pow round: P_2 = A@A (blocks 0..15) ; P_1 = A (16..31) ----
__global__ __launch_bounds__(256) void pow_first(
    const float* __restrict__ A, float* __restrict__ P)
{
  int bid = blockIdx.x, tid = threadIdx.x;
  if (bid >= 16) {
    int blk = bid - 16;
#pragma unroll
    for (int q = 0; q < 4; ++q) {
      int idx = blk * 1024 + q * 256 + tid;
      *(float4*)(P + (size_t)idx * 4) = *(const float4*)(A + (size_t)idx * 4);
    }
    return;
  }
  int tile = bid;
  int tr = (tile >> 2) * 64;
  int tc = (tile & 3) * 64;
  __shared__ float As[64][33];
  __shared__ float Bs[32][65];
  int tx = tid & 15, ty = tid >> 4;
  float acc[4][4] = {};
  for (int k0 = 0; k0 < 256; k0 += 32) {
#pragma unroll
    for (int p = 0; p < 2; ++p) {
      int idx = tid + p * 256;
      int r = idx >> 3, c4 = (idx & 7) * 4;
      float4 v = *(const float4*)(A + (size_t)(tr + r) * 256 + k0 + c4);
      As[r][c4 + 0] = v.x; As[r][c4 + 1] = v.y; As[r][c4 + 2] = v.z; As[r][c4 + 3] = v.w;
    }
#pragma unroll
    for (int p = 0; p < 2; ++p) {
      int idx = tid + p * 256;
      int r = idx >> 4, c4 = (idx & 15) * 4;
      float4 v = *(const float4*)(A + (size_t)(k0 + r) * 256 + tc + c4);
      Bs[r][c4 + 0] = v.x; Bs[r][c4 + 1] = v.y; Bs[r][c4 + 2] = v.z; Bs[r][c4 + 3] = v.w;
    }
    __syncthreads();
#pragma unroll
    for (int kk = 0; kk < 32; ++kk) {
      float a[4], b[4];
#pragma unroll
      for (int u = 0; u < 4; ++u) a[u] = As[ty * 4 + u][kk];
#pragma unroll
      for (int v = 0; v < 4; ++v) b[v] = Bs[kk][tx * 4 + v];
#pragma unroll
      for (int u = 0; u < 4; ++u)
#pragma unroll
        for (int v = 0; v < 4; ++v) acc[u][v] += a[u] * b[v];
    }
    __syncthreads();
  }
#pragma unroll
  for (int u = 0; u < 4; ++u)
#pragma unroll
    for (int v = 0; v < 4; ++v)
      P[(size_t)MATF + (size_t)(tr + ty * 4 + u) * 256 + tc + tx * 4 + v] = acc[u][v];
}

// ---------- Kv[j] = A^j B ----------
__global__ __launch_bounds__(256) void kv_kernel(
    const float* __restrict__ P, const float* __restrict__ Bv,
    float* __restrict__ Kv)
{
  int j = blockIdx.x;
  int n = threadIdx.x;
  __shared__ float bs[256];
  bs[n] = Bv[n];
  __syncthreads();
  if (j == 0) { Kv[n] = bs[n]; return; }
  const float* M = P + (size_t)(j - 1) * MATF;
  float acc = 0.f;
  for (int m = 0; m < 256; ++m) acc += M[(size_t)n * 256 + m] * bs[m];
  Kv[(size_t)j * 256 + n] = acc;
}

// ---------- chunk-end local states e_k[n][b] ----------
__global__ __launch_bounds__(256) void e_kernel(
    const float* __restrict__ in, const float* __restrict__ Kv,
    float* __restrict__ e)
{
  int k = blockIdx.x >> 6;
  int b = blockIdx.x & 63;
  int n = threadIdx.x;
  __shared__ float fs[64];
  if (n < 64) fs[n] = in[(size_t)(k * 64 + n) * 64 + b];
  __syncthreads();
  float acc = 0.f;
#pragma unroll
  for (int j = 0; j < 64; ++j) acc += Kv[(size_t)j * 256 + n] * fs[63 - j];
  e[((size_t)k * 256 + n) * 64 + b] = acc;
}

// ---------- scan round + riders: squaring + Gt-build slice ----------
__global__ __launch_bounds__(256) void scan_round(
    const float* __restrict__ win, float* __restrict__ wout,
    const float* __restrict__ M, int d,
    float* __restrict__ MSdst,
    const float* __restrict__ P, const float* __restrict__ Kv,
    unsigned short* __restrict__ Gt, int gt_row0, int gt_off)
{
  __shared__ float As[64][33];
  __shared__ float Bs[32][65];
  int bid = blockIdx.x;
  int tid = threadIdx.x;

  if (bid >= gt_off) {
    int r2 = gt_row0 + (bid - gt_off);
    if (r2 >= 16384) return;
    int i = r2 >> 8, n = r2 & 255;
    unsigned short* dst = Gt + (size_t)r2 * 640;
    for (int c = tid; c < 320; c += 256) {
      float x;
      if (c < 64) x = (c <= i) ? Kv[(size_t)(i - c) * 256 + n] : 0.f;
      else        x = P[(size_t)i * MATF + (size_t)n * 256 + (c - 64)];
      unsigned short hi = f2bf(x);
      float lo = x - bf2f(hi);
      dst[c]       = hi;
      dst[320 + c] = f2bf(lo);
    }
    return;
  }
  if (bid >= 256) {
    int tile = bid - 256;
    int tr = (tile >> 2) * 64;
    int tc = (tile & 3) * 64;
    int tx = tid & 15, ty = tid >> 4;
    float acc[4][4] = {};
    for (int k0 = 0; k0 < 256; k0 += 32) {
#pragma unroll
      for (int p = 0; p < 2; ++p) {
        int idx = tid + p * 256;
        int r = idx >> 3, c4 = (idx & 7) * 4;
        float4 v = *(const float4*)(M + (size_t)(tr + r) * 256 + k0 + c4);
        As[r][c4 + 0] = v.x; As[r][c4 + 1] = v.y; As[r][c4 + 2] = v.z; As[r][c4 + 3] = v.w;
      }
#pragma unroll
      for (int p = 0; p < 2; ++p) {
        int idx = tid + p * 256;
        int r = idx >> 4, c4 = (idx & 15) * 4;
        float4 v = *(const float4*)(M + (size_t)(k0 + r) * 256 + tc + c4);
        Bs[r][c4 + 0] = v.x; Bs[r][c4 + 1] = v.y; Bs[r][c4 + 2] = v.z; Bs[r][c4 + 3] = v.w;
      }
      __syncthreads();
#pragma unroll
      for (int kk = 0; kk < 32; ++kk) {
        float a[4], b[4];
#pragma unroll
        for (int u = 0; u < 4; ++u) a[u] = As[ty * 4 + u][kk];
#pragma unroll
        for (int v = 0; v < 4; ++v) b[v] = Bs[kk][tx * 4 + v];
#pragma unroll
        for (int u = 0; u < 4; ++u)
#pragma unroll
          for (int v = 0; v < 4; ++v) acc[u][v] += a[u] * b[v];
      }
      __syncthreads();
    }
#pragma unroll
    for (int u = 0; u < 4; ++u)
#pragma unroll
      for (int v = 0; v < 4; ++v)
        MSdst[(size_t)(tr + ty * 4 + u) * 256 + tc + tx * 4 + v] = acc[u][v];
    return;
  }

  int k  = bid >> 2;
  int rt = bid & 3;
  const float* src = win  + (size_t)k * 16384;
  float*       dst = wout + (size_t)k * 16384;
  if (k < d) {
#pragma unroll
    for (int p = 0; p < 16; ++p) {
      int idx = rt * 4096 + p * 256 + tid;
      dst[idx] = src[idx];
    }
    return;
  }
  const float* v = win + (size_t)(k - d) * 16384;
  int tx = tid & 15, ty = tid >> 4;
  float acc[4][4] = {};
  for (int k0 = 0; k0 < 256; k0 += 32) {
#pragma unroll
    for (int p = 0; p < 2; ++p) {
      int idx = tid + p * 256;
      int r = idx >> 3, c4 = (idx & 7) * 4;
      float4 t4 = *(const float4*)(M + (size_t)(rt * 64 + r) * 256 + k0 + c4);
      As[r][c4 + 0] = t4.x; As[r][c4 + 1] = t4.y; As[r][c4 + 2] = t4.z; As[r][c4 + 3] = t4.w;
    }
#pragma unroll
    for (int p = 0; p < 2; ++p) {
      int idx = tid + p * 256;
      int r = idx >> 4, c4 = (idx & 15) * 4;
      float4 t4 = *(const float4*)(v + (size_t)(k0 + r) * 64 + c4);
      Bs[r][c4 + 0] = t4.x; Bs[r][c4 + 1] = t4.y; Bs[r][c4 + 2] = t4.z; Bs[r][c4 + 3] = t4.w;
    }
    __syncthreads();
#pragma unroll
    for (int kk = 0; kk < 32; ++kk) {
      float a[4], b[4];
#pragma unroll
      for (int u = 0; u < 4; ++u) a[u] = As[ty * 4 + u][kk];
#pragma unroll
      for (int v2 = 0; v2 < 4; ++v2) b[v2] = Bs[kk][tx * 4 + v2];
#pragma unroll
      for (int u = 0; u < 4; ++u)
#pragma unroll
        for (int v2 = 0; v2 < 4; ++v2) acc[u][v2] += a[u] * b[v2];
    }
    __syncthreads();
  }
#pragma unroll
  for (int u = 0; u < 4; ++u)
#pragma unroll
    for (int v2 = 0; v2 < 4; ++v2) {
      int idx = (rt * 64 + ty * 4 + u) * 64 + tx * 4 + v2;
      dst[idx] = src[idx] + acc[u][v2];
    }
}

// ---------- build Ht ----------
__global__ __launch_bounds__(320) void build_ht(
    const float* __restrict__ in, const float* __restrict__ w,
    unsigned short* __restrict__ Ht)
{
  int row = blockIdx.x;
  int k = row >> 6, b = row & 63;
  int j = threadIdx.x;
  float x;
  if (j < 64) x = in[(size_t)(k * 64 + j) * 64 + b];
  else        x = (k > 0) ? w[((size_t)(k - 1) * 256 + (j - 64)) * 64 + b] : 0.f;
  unsigned short hi = f2bf(x);
  float lo = x - bf2f(hi);
  Ht[(size_t)row * 640 + j]       = hi;
  Ht[(size_t)row * 640 + 320 + j] = f2bf(lo);
}

// ---------- out = Ht @ Gt^T, split-bf16 MFMA, dbuf + XCD-owns-M mapping ----
// xcd = bid&7 (HW round-robin), idx = bid>>3:
//   mt = 4*xcd + (idx>>7)  -> XCD's Ht slice (4x 164KB, L2-resident)
//   nt = idx & 127         -> fast sweep; all XCDs stream the same Gt panels
//                             in lockstep -> L3-shared 8-way.
__global__ __launch_bounds__(256) void out_gemm(
    const unsigned short* __restrict__ Ht,
    const unsigned short* __restrict__ Gt,
    float* __restrict__ out)
{
  __shared__ char smem[65536];

  int bid = blockIdx.x;
  int xcd = bid & 7;
  int idx = bid >> 3;
  int mt = xcd * 4 + (idx >> 7);   // 0..31
  int nt = idx & 127;              // 0..127
  int mrow0 = mt * 128, nrow0 = nt * 128;

  int tid = threadIdx.x;
  int w = tid >> 6, l = tid & 63;
  int wm = w >> 1, wn = w & 1;

  auto stage = [&](const unsigned short* src, int row0, char* lds, int k0) {
#pragma unroll
    for (int it = 0; it < 4; ++it) {
      int L = it * 4096 + tid * 16;
      int row = L >> 7;
      int p = (L >> 4) & 7;
      int o = p ^ (row & 7);
      int h = o >> 2, q = o & 3;
      const void* g = src + (size_t)(row0 + row) * 640 + h * 320 + k0 + q * 8;
      void* dst = lds + (it * 4096 + w * 1024);
      load16_lds(g, dst);
    }
  };

  stage(Ht, mrow0, smem, 0);
  stage(Gt, nrow0, smem + 16384, 0);
  __syncthreads();   // implicit vmcnt(0): buf0 ready

  f32x4 acc[4][4] = {};
  int rAbase = wm * 64 + (l & 15);
  int rBbase = wn * 64 + (l & 15);
  int qo = l >> 4;

  for (int ks = 0; ks < 10; ++ks) {
    char* cur = smem + (ks & 1) * 32768;
    if (ks < 9) {
      char* nxt = smem + ((ks + 1) & 1) * 32768;
      stage(Ht, mrow0, nxt, (ks + 1) * 32);
      stage(Gt, nrow0, nxt + 16384, (ks + 1) * 32);
    }
    char* Ab = cur;
    char* Bb = cur + 16384;
    short8 ah[4], al[4], bh[4], bl[4];
#pragma unroll
    for (int mf = 0; mf < 4; ++mf) {
      int r = rAbase + mf * 16;
      int ph = (qo)     ^ (r & 7);
      int pl = (4 + qo) ^ (r & 7);
      ah[mf] = *(const short8*)(Ab + r * 128 + ph * 16);
      al[mf] = *(const short8*)(Ab + r * 128 + pl * 16);
    }
#pragma unroll
    for (int nf = 0; nf < 4; ++nf) {
      int r = rBbase + nf * 16;
      int ph = (qo)     ^ (r & 7);
      int pl = (4 + qo) ^ (r & 7);
      bh[nf] = *(const short8*)(Bb + r * 128 + ph * 16);
      bl[nf] = *(const short8*)(Bb + r * 128 + pl * 16);
    }
#pragma unroll
    for (int mf = 0; mf < 4; ++mf)
#pragma unroll
      for (int nf = 0; nf < 4; ++nf) {
        acc[mf][nf] = __builtin_amdgcn_mfma_f32_16x16x32_bf16(ah[mf], bh[nf], acc[mf][nf], 0, 0, 0);
        acc[mf][nf] = __builtin_amdgcn_mfma_f32_16x16x32_bf16(ah[mf], bl[nf], acc[mf][nf], 0, 0, 0);
        acc[mf][nf] = __builtin_amdgcn_mfma_f32_16x16x32_bf16(al[mf], bh[nf], acc[mf][nf], 0, 0, 0);
      }
    __syncthreads();
  }

  int Mbase = mrow0 + wm * 64 + (l >> 4) * 4;
  int Nbase = nrow0 + wn * 64 + (l & 15);
#pragma unroll
  for (int mf = 0; mf < 4; ++mf)
#pragma unroll
    for (int nf = 0; nf < 4; ++nf)
#pragma unroll
      for (int r = 0; r < 4; ++r) {
        int Mrow = Mbase + mf * 16 + r;
        int Ncol = Nbase + nf * 16;
        int k = Mrow >> 6, b = Mrow & 63;
        int i = Ncol >> 8, n = Ncol & 255;
        out[((size_t)k * 4096 + (size_t)i * 64 + b) * 256 + n] = acc[mf][nf][r];
      }
}

extern "C" void kernel_launch(void* const* d_in, const int* in_sizes, int n_in,
                              void* d_out, int out_size, void* d_ws, size_t ws_size,
                              hipStream_t stream)
{
  const float* in = (const float*)d_in[0];
  const float* A  = (const float*)d_in[1];
  const float* Bv = (const float*)d_in[2];
  float* out = (float*)d_out;
  float* ws  = (float*)d_ws;

  float* P  = ws;                          // A^1..A^64
  float* Kv = P  + (size_t)64 * MATF;
  float* e  = Kv + (size_t)64 * 256;       // scan buf 0
  float* w2 = e  + (size_t)64 * 16384;     // scan buf 1
  float* MS = w2 + (size_t)64 * 16384;     // squaring ping-pong
  unsigned short* Ht = (unsigned short*)(MS + (size_t)2 * MATF);
  unsigned short* Gt = Ht + (size_t)4096 * 640;

  pow_first<<<dim3(32), dim3(256), 0, stream>>>(A, P);
  for (int m = 2; m <= 32; m <<= 1) {
    gemm_nn_batch<<<dim3(m * 16), dim3(256), 0, stream>>>(
        P + (size_t)(m - 1) * MATF, P, P + (size_t)m * MATF, m);
  }
  kv_kernel<<<dim3(64), dim3(256), 0, stream>>>(P, Bv, Kv);
  e_kernel<<<dim3(4096), dim3(256), 0, stream>>>(in, Kv, e);

  float* bufs[2] = {e, w2};
  for (int r = 0; r < 6; ++r) {
    const float* M = (r == 0) ? (P + (size_t)63 * MATF)
                              : (MS + (size_t)((r - 1) & 1) * MATF);
    float* MSdst = MS + (size_t)(r & 1) * MATF;
    int gt_row0 = r * 2731;
    int gt_cnt  = (r < 5) ? 2731 : (16384 - 5 * 2731);
    int gt_off  = (r < 5) ? 272 : 256;
    int grid    = gt_off + gt_cnt;
    scan_round<<<dim3(grid), dim3(256), 0, stream>>>(
        bufs[r & 1], bufs[(r + 1) & 1], M, 1 << r,
        MSdst, P, Kv, Gt, gt_row0, gt_off);
  }

  build_ht<<<dim3(4096), dim3(320), 0, stream>>>(in, e, Ht);

  out_gemm<<<dim3(4096), dim3(256), 0, stream>>>(Ht, Gt, out);
}

// Round 11
// 384.436 us; speedup vs baseline: 1.0539x; 1.0539x over previous
//
#include <hip/hip_runtime.h>
#include <hip/hip_bf16.h>

// HiPPO-LegT parallel chunked scan, round 11.
// = R10 chain verbatim; out_gemm rebuilt with 256x256 tiles (8 waves, 512
//   threads, single-buffer 2-barrier schedule = R2's proven shape scaled up).
//   Operand bytes per output byte: 5.1 -> 2.56 (halves operand re-fetch).
//
// ws layout (floats):
//   P   : A^1..A^64          (64 * 65536)
//   Kv  : A^j B, j=0..63     (64 * 256)
//   e   : scan buffer 0      (64 * 256 * 64)
//   w2  : scan buffer 1      (64 * 256 * 64)
//   MS  : squaring ping-pong (2 * 65536)
//   Ht  : bf16 [4096][640]   (hi 0..319 | lo 320..639)   (ushort)
//   Gt  : bf16 [16384][640]                               (ushort)

#define MATF 65536

typedef __attribute__((ext_vector_type(8))) short short8;
typedef __attribute__((ext_vector_type(4))) float f32x4;

__device__ __forceinline__ unsigned short f2bf(float x) {
  union { __hip_bfloat16 h; unsigned short u; } cv;
  cv.h = __float2bfloat16(x);
  return cv.u;
}
__device__ __forceinline__ float bf2f(unsigned short u) {
  union { unsigned short u; __hip_bfloat16 h; } cv;
  cv.u = u;
  return __bfloat162float(cv.h);
}

__device__ __forceinline__ void load16_lds(const void* gsrc, void* ldst) {
  __builtin_amdgcn_global_load_lds(
      (const __attribute__((address_space(1))) unsigned int*)gsrc,
      (__attribute__((address_space(3))) unsigned int*)ldst,
      16, 0, 0);
}

// ---------- batched 256x256x256 GEMM: Z[g] = X @ Y[g] (fp32) ----------
__global__ __launch_bounds__(256) void gemm_nn_batch(
    const float* __restrict__ X, const float* __restrict__ Ys,
    float* __restrict__ Zs, int count)
{
  int g    = blockIdx.x >> 4;
  int tile = blockIdx.x & 15;
  if (g >= count) return;
  const float* Y = Ys + (size_t)g * MATF;
  float*       Z = Zs + (size_t)g * MATF;
  int tr = (tile >> 2) * 64;
  int tc = (tile & 3) * 64;

  __shared__ float As[64][33];
  __shared__ float Bs[32][65];
  int tid = threadIdx.x;
  int tx = tid & 15, ty = tid >> 4;
  float acc[4][4] = {};

  for (int k0 = 0; k0 < 256; k0 += 32) {
#pragma unroll
    for (int p = 0; p < 2; ++p) {
      int idx = tid + p * 256;
      int r = idx >> 3, c4 = (idx & 7) * 4;
      float4 v = *(const float4*)(X + (size_t)(tr + r) * 256 + k0 + c4);
      As[r][c4 + 0] = v.x; As[r][c4 + 1] = v.y; As[r][c4 + 2] = v.z; As[r][c4 + 3] = v.w;
    }
#pragma unroll
    for (int p = 0; p < 2; ++p) {
      int idx = tid + p * 256;
      int r = idx >> 4, c4 = (idx & 15) * 4;
      float4 v = *(const float4*)(Y + (size_t)(k0 + r) * 256 + tc + c4);
      Bs[r][c4 + 0] = v.x; Bs[r][c4 + 1] = v.y; Bs[r][c4 + 2] = v.z; Bs[r][c4 + 3] = v.w;
    }
    __syncthreads();
#pragma unroll
    for (int kk = 0; kk < 32; ++kk) {
      float a[4], b[4];
#pragma unroll
      for (int u = 0; u < 4; ++u) a[u] = As[ty * 4 + u][kk];
#pragma unroll
      for (int v = 0; v < 4; ++v) b[v] = Bs[kk][tx * 4 + v];
#pragma unroll
      for (int u = 0; u < 4; ++u)
#pragma unroll
        for (int v = 0; v < 4; ++v) acc[u][v] += a[u] * b[v];
    }
    __syncthreads();
  }
#pragma unroll
  for (int u = 0; u < 4; ++u)
#pragma unroll
    for (int v = 0; v < 4; ++v)
      Z[(size_t)(tr + ty * 4 + u) * 256 + tc + tx * 4 + v] = acc[u][v];
}

// ---------- first pow round: P_2 = A@A (blocks 0..15) ; P_1 = A (16..31) ----
__global__ __launch_bounds__(256) void pow_first(
    const float* __restrict__ A, float* __restrict__ P)
{
  int bid = blockIdx.x, tid = threadIdx.x;
  if (bid >= 16) {
    int blk = bid - 16;
#pragma unroll
    for (int q = 0; q < 4; ++q) {
      int idx = blk * 1024 + q * 256 + tid;
      *(float4*)(P + (size_t)idx * 4) = *(const float4*)(A + (size_t)idx * 4);
    }
    return;
  }
  int tile = bid;
  int tr = (tile >> 2) * 64;
  int tc = (tile & 3) * 64;
  __shared__ float As[64][33];
  __shared__ float Bs[32][65];
  int tx = tid & 15, ty = tid >> 4;
  float acc[4][4] = {};
  for (int k0 = 0; k0 < 256; k0 += 32) {
#pragma unroll
    for (int p = 0; p < 2; ++p) {
      int idx = tid + p * 256;
      int r = idx >> 3, c4 = (idx & 7) * 4;
      float4 v = *(const float4*)(A + (size_t)(tr + r) * 256 + k0 + c4);
      As[r][c4 + 0] = v.x; As[r][c4 + 1] = v.y; As[r][c4 + 2] = v.z; As[r][c4 + 3] = v.w;
    }
#pragma unroll
    for (int p = 0; p < 2; ++p) {
      int idx = tid + p * 256;
      int r = idx >> 4, c4 = (idx & 15) * 4;
      float4 v = *(const float4*)(A + (size_t)(k0 + r) * 256 + tc + c4);
      Bs[r][c4 + 0] = v.x; Bs[r][c4 + 1] = v.y; Bs[r][c4 + 2] = v.z; Bs[r][c4 + 3] = v.w;
    }
    __syncthreads();
#pragma unroll
    for (int kk = 0; kk < 32; ++kk) {
      float a[4], b[4];
#pragma unroll
      for (int u = 0; u < 4; ++u) a[u] = As[ty * 4 + u][kk];
#pragma unroll
      for (int v = 0; v < 4; ++v) b[v] = Bs[kk][tx * 4 + v];
#pragma unroll
      for (int u = 0; u < 4; ++u)
#pragma unroll
        for (int v = 0; v < 4; ++v) acc[u][v] += a[u] * b[v];
    }
    __syncthreads();
  }
#pragma unroll
  for (int u = 0; u < 4; ++u)
#pragma unroll
    for (int v = 0; v < 4; ++v)
      P[(size_t)MATF + (size_t)(tr + ty * 4 + u) * 256 + tc + tx * 4 + v] = acc[u][v];
}

// ---------- Kv[j] = A^j B ----------
__global__ __launch_bounds__(256) void kv_kernel(
    const float* __restrict__ P, const float* __restrict__ Bv,
    float* __restrict__ Kv)
{
  int j = blockIdx.x;
  int n = threadIdx.x;
  __shared__ float bs[256];
  bs[n] = Bv[n];
  __syncthreads();
  if (j == 0) { Kv[n] = bs[n]; return; }
  const float* M = P + (size_t)(j - 1) * MATF;
  float acc = 0.f;
  for (int m = 0; m < 256; ++m) acc += M[(size_t)n * 256 + m] * bs[m];
  Kv[(size_t)j * 256 + n] = acc;
}

// ---------- chunk-end local states e_k[n][b] ----------
__global__ __launch_bounds__(256) void e_kernel(
    const float* __restrict__ in, const float* __restrict__ Kv,
    float* __restrict__ e)
{
  int k = blockIdx.x >> 6;
  int b = blockIdx.x & 63;
  int n = threadIdx.x;
  __shared__ float fs[64];
  if (n < 64) fs[n] = in[(size_t)(k * 64 + n) * 64 + b];
  __syncthreads();
  float acc = 0.f;
#pragma unroll
  for (int j = 0; j < 64; ++j) acc += Kv[(size_t)j * 256 + n] * fs[63 - j];
  e[((size_t)k * 256 + n) * 64 + b] = acc;
}

// ---------- scan round + riders: squaring + Gt-build slice ----------
__global__ __launch_bounds__(256) void scan_round(
    const float* __restrict__ win, float* __restrict__ wout,
    const float* __restrict__ M, int d,
    float* __restrict__ MSdst,
    const float* __restrict__ P, const float* __restrict__ Kv,
    unsigned short* __restrict__ Gt, int gt_row0, int gt_off)
{
  __shared__ float As[64][33];
  __shared__ float Bs[32][65];
  int bid = blockIdx.x;
  int tid = threadIdx.x;

  if (bid >= gt_off) {
    int r2 = gt_row0 + (bid - gt_off);
    if (r2 >= 16384) return;
    int i = r2 >> 8, n = r2 & 255;
    unsigned short* dst = Gt + (size_t)r2 * 640;
    for (int c = tid; c < 320; c += 256) {
      float x;
      if (c < 64) x = (c <= i) ? Kv[(size_t)(i - c) * 256 + n] : 0.f;
      else        x = P[(size_t)i * MATF + (size_t)n * 256 + (c - 64)];
      unsigned short hi = f2bf(x);
      float lo = x - bf2f(hi);
      dst[c]       = hi;
      dst[320 + c] = f2bf(lo);
    }
    return;
  }
  if (bid >= 256) {
    int tile = bid - 256;
    int tr = (tile >> 2) * 64;
    int tc = (tile & 3) * 64;
    int tx = tid & 15, ty = tid >> 4;
    float acc[4][4] = {};
    for (int k0 = 0; k0 < 256; k0 += 32) {
#pragma unroll
      for (int p = 0; p < 2; ++p) {
        int idx = tid + p * 256;
        int r = idx >> 3, c4 = (idx & 7) * 4;
        float4 v = *(const float4*)(M + (size_t)(tr + r) * 256 + k0 + c4);
        As[r][c4 + 0] = v.x; As[r][c4 + 1] = v.y; As[r][c4 + 2] = v.z; As[r][c4 + 3] = v.w;
      }
#pragma unroll
      for (int p = 0; p < 2; ++p) {
        int idx = tid + p * 256;
        int r = idx >> 4, c4 = (idx & 15) * 4;
        float4 v = *(const float4*)(M + (size_t)(k0 + r) * 256 + tc + c4);
        Bs[r][c4 + 0] = v.x; Bs[r][c4 + 1] = v.y; Bs[r][c4 + 2] = v.z; Bs[r][c4 + 3] = v.w;
      }
      __syncthreads();
#pragma unroll
      for (int kk = 0; kk < 32; ++kk) {
        float a[4], b[4];
#pragma unroll
        for (int u = 0; u < 4; ++u) a[u] = As[ty * 4 + u][kk];
#pragma unroll
        for (int v = 0; v < 4; ++v) b[v] = Bs[kk][tx * 4 + v];
#pragma unroll
        for (int u = 0; u < 4; ++u)
#pragma unroll
          for (int v = 0; v < 4; ++v) acc[u][v] += a[u] * b[v];
      }
      __syncthreads();
    }
#pragma unroll
    for (int u = 0; u < 4; ++u)
#pragma unroll
      for (int v = 0; v < 4; ++v)
        MSdst[(size_t)(tr + ty * 4 + u) * 256 + tc + tx * 4 + v] = acc[u][v];
    return;
  }

  int k  = bid >> 2;
  int rt = bid & 3;
  const float* src = win  + (size_t)k * 16384;
  float*       dst = wout + (size_t)k * 16384;
  if (k < d) {
#pragma unroll
    for (int p = 0; p < 16; ++p) {
      int idx = rt * 4096 + p * 256 + tid;
      dst[idx] = src[idx];
    }
    return;
  }
  const float* v = win + (size_t)(k - d) * 16384;
  int tx = tid & 15, ty = tid >> 4;
  float acc[4][4] = {};
  for (int k0 = 0; k0 < 256; k0 += 32) {
#pragma unroll
    for (int p = 0; p < 2; ++p) {
      int idx = tid + p * 256;
      int r = idx >> 3, c4 = (idx & 7) * 4;
      float4 t4 = *(const float4*)(M + (size_t)(rt * 64 + r) * 256 + k0 + c4);
      As[r][c4 + 0] = t4.x; As[r][c4 + 1] = t4.y; As[r][c4 + 2] = t4.z; As[r][c4 + 3] = t4.w;
    }
#pragma unroll
    for (int p = 0; p < 2; ++p) {
      int idx = tid + p * 256;
      int r = idx >> 4, c4 = (idx & 15) * 4;
      float4 t4 = *(const float4*)(v + (size_t)(k0 + r) * 64 + c4);
      Bs[r][c4 + 0] = t4.x; Bs[r][c4 + 1] = t4.y; Bs[r][c4 + 2] = t4.z; Bs[r][c4 + 3] = t4.w;
    }
    __syncthreads();
#pragma unroll
    for (int kk = 0; kk < 32; ++kk) {
      float a[4], b[4];
#pragma unroll
      for (int u = 0; u < 4; ++u) a[u] = As[ty * 4 + u][kk];
#pragma unroll
      for (int v2 = 0; v2 < 4; ++v2) b[v2] = Bs[kk][tx * 4 + v2];
#pragma unroll
      for (int u = 0; u < 4; ++u)
#pragma unroll
        for (int v2 = 0; v2 < 4; ++v2) acc[u][v2] += a[u] * b[v2];
    }
    __syncthreads();
  }
#pragma unroll
  for (int u = 0; u < 4; ++u)
#pragma unroll
    for (int v2 = 0; v2 < 4; ++v2) {
      int idx = (rt * 64 + ty * 4 + u) * 64 + tx * 4 + v2;
      dst[idx] = src[idx] + acc[u][v2];
    }
}

// ---------- build Ht ----------
__global__ __launch_bounds__(320) void build_ht(
    const float* __restrict__ in, const float* __restrict__ w,
    unsigned short* __restrict__ Ht)
{
  int row = blockIdx.x;
  int k = row >> 6, b = row & 63;
  int j = threadIdx.x;
  float x;
  if (j < 64) x = in[(size_t)(k * 64 + j) * 64 + b];
  else        x = (k > 0) ? w[((size_t)(k - 1) * 256 + (j - 64)) * 64 + b] : 0.f;
  unsigned short hi = f2bf(x);
  float lo = x - bf2f(hi);
  Ht[(size_t)row * 640 + j]       = hi;
  Ht[(size_t)row * 640 + 320 + j] = f2bf(lo);
}

// ---------- out = Ht @ Gt^T, 256x256 tile, 8 waves, split-bf16 MFMA ----------
// Single 64KB buffer (A 32KB | B 32KB), R2's proven 2-barrier schedule.
// Per tile: [256 rows][8 octets of 16B], octet o = h*4+q, phys p = o^(row&7).
// Waves: w=tid>>6; wm=w>>2 (0..1) -> 128 M-rows; wn=w&3 (0..3) -> 64 N-rows.
__global__ __launch_bounds__(512) void out_gemm(
    const unsigned short* __restrict__ Ht,
    const unsigned short* __restrict__ Gt,
    float* __restrict__ out)
{
  __shared__ char smem[65536];
  char* Ab = smem;
  char* Bb = smem + 32768;

  int bid = blockIdx.x;
  int swz = (bid & 7) * 128 + (bid >> 3);   // 1024 % 8 == 0, bijective
  int mt = swz >> 6;                        // 0..15
  int nt = swz & 63;                        // 0..63
  int mrow0 = mt * 256, nrow0 = nt * 256;

  int tid = threadIdx.x;
  int w = tid >> 6, l = tid & 63;
  int wm = w >> 2, wn = w & 3;

  auto stage = [&](const unsigned short* src, int row0, char* lds, int k0) {
#pragma unroll
    for (int it = 0; it < 4; ++it) {
      int L = it * 8192 + tid * 16;         // linear byte offset in 32KB tile
      int row = L >> 7;                     // 0..255
      int p = (L >> 4) & 7;
      int o = p ^ (row & 7);
      int h = o >> 2, q = o & 3;
      const void* g = src + (size_t)(row0 + row) * 640 + h * 320 + k0 + q * 8;
      void* dst = lds + (it * 8192 + w * 1024);   // wave-uniform base
      load16_lds(g, dst);
    }
  };

  stage(Ht, mrow0, Ab, 0);
  stage(Gt, nrow0, Bb, 0);

  f32x4 acc[8][4] = {};
  int rAbase = wm * 128 + (l & 15);
  int rBbase = wn * 64 + (l & 15);
  int qo = l >> 4;  // k-octet 0..3

  for (int ks = 0; ks < 10; ++ks) {
    __syncthreads();   // implicit vmcnt(0): tile ks ready
    short8 bh[4], bl[4];
#pragma unroll
    for (int nf = 0; nf < 4; ++nf) {
      int r = rBbase + nf * 16;
      int ph = (qo)     ^ (r & 7);
      int pl = (4 + qo) ^ (r & 7);
      bh[nf] = *(const short8*)(Bb + r * 128 + ph * 16);
      bl[nf] = *(const short8*)(Bb + r * 128 + pl * 16);
    }
#pragma unroll
    for (int mf = 0; mf < 8; ++mf) {
      int r = rAbase + mf * 16;
      int ph = (qo)     ^ (r & 7);
      int pl = (4 + qo) ^ (r & 7);
      short8 ah = *(const short8*)(Ab + r * 128 + ph * 16);
      short8 al = *(const short8*)(Ab + r * 128 + pl * 16);
#pragma unroll
      for (int nf = 0; nf < 4; ++nf) {
        acc[mf][nf] = __builtin_amdgcn_mfma_f32_16x16x32_bf16(ah, bh[nf], acc[mf][nf], 0, 0, 0);
        acc[mf][nf] = __builtin_amdgcn_mfma_f32_16x16x32_bf16(ah, bl[nf], acc[mf][nf], 0, 0, 0);
        acc[mf][nf] = __builtin_amdgcn_mfma_f32_16x16x32_bf16(al, bh[nf], acc[mf][nf], 0, 0, 0);
      }
    }
    __syncthreads();   // all waves done reading tile ks
    if (ks < 9) {
      stage(Ht, mrow0, Ab, (ks + 1) * 32);
      stage(Gt, nrow0, Bb, (ks + 1) * 32);
    }
  }

  // epilogue: C/D col = lane&15 (N), row = (lane>>4)*4+reg (M)
  int Mbase = mrow0 + wm * 128 + (l >> 4) * 4;
  int Nbase = nrow0 + wn * 64 + (l & 15);
#pragma unroll
  for (int mf = 0; mf < 8; ++mf)
#pragma unroll
    for (int nf = 0; nf < 4; ++nf)
#pragma unroll
      for (int r = 0; r < 4; ++r) {
        int Mrow = Mbase + mf * 16 + r;
        int Ncol = Nbase + nf * 16;
        int k = Mrow >> 6, b = Mrow & 63;
        int i = Ncol >> 8, n = Ncol & 255;
        out[((size_t)k * 4096 + (size_t)i * 64 + b) * 256 + n] = acc[mf][nf][r];
      }
}

extern "C" void kernel_launch(void* const* d_in, const int* in_sizes, int n_in,
                              void* d_out, int out_size, void* d_ws, size_t ws_size,
                              hipStream_t stream)
{
  const float* in = (const float*)d_in[0];
  const float* A  = (const float*)d_in[1];
  const float* Bv = (const float*)d_in[2];
  float* out = (float*)d_out;
  float* ws  = (float*)d_ws;

  float* P  = ws;                          // A^1..A^64
  float* Kv = P  + (size_t)64 * MATF;
  float* e  = Kv + (size_t)64 * 256;       // scan buf 0
  float* w2 = e  + (size_t)64 * 16384;     // scan buf 1
  float* MS = w2 + (size_t)64 * 16384;     // squaring ping-pong
  unsigned short* Ht = (unsigned short*)(MS + (size_t)2 * MATF);
  unsigned short* Gt = Ht + (size_t)4096 * 640;

  pow_first<<<dim3(32), dim3(256), 0, stream>>>(A, P);
  for (int m = 2; m <= 32; m <<= 1) {
    gemm_nn_batch<<<dim3(m * 16), dim3(256), 0, stream>>>(
        P + (size_t)(m - 1) * MATF, P, P + (size_t)m * MATF, m);
  }
  kv_kernel<<<dim3(64), dim3(256), 0, stream>>>(P, Bv, Kv);
  e_kernel<<<dim3(4096), dim3(256), 0, stream>>>(in, Kv, e);

  float* bufs[2] = {e, w2};
  for (int r = 0; r < 6; ++r) {
    const float* M = (r == 0) ? (P + (size_t)63 * MATF)
                              : (MS + (size_t)((r - 1) & 1) * MATF);
    float* MSdst = MS + (size_t)(r & 1) * MATF;
    int gt_row0 = r * 2731;
    int gt_cnt  = (r < 5) ? 2731 : (16384 - 5 * 2731);
    int gt_off  = (r < 5) ? 272 : 256;
    int grid    = gt_off + gt_cnt;
    scan_round<<<dim3(grid), dim3(256), 0, stream>>>(
        bufs[r & 1], bufs[(r + 1) & 1], M, 1 << r,
        MSdst, P, Kv, Gt, gt_row0, gt_off);
  }

  build_ht<<<dim3(4096), dim3(320), 0, stream>>>(in, e, Ht);

  out_gemm<<<dim3(1024), dim3(512), 0, stream>>>(Ht, Gt, out);
}